// Round 4
// baseline (47.505 us; speedup 1.0000x reference)
//
#include <hip/hip_runtime.h>

#define T_LEN   524288
#define BATCH   32
#define WIN     1024
#define STRIDE  256
#define NCODE   32
#define NFRAMES 2049                 // T_LEN/STRIDE + 1
#define NFR_TOT (BATCH * NFRAMES)    // 65568 frames
#define NBLK    2048                 // 256-sample product-blocks per row
#define NG      (BATCH * NBLK)       // 65536 block-product groups
#define RECW    36                   // padded record width (33 lags -> 36 floats)

// ---------------------------------------------------------------------------
// Pass 1: lag-block products, record layout  B[g*36 + k] =
//   sum_{m=256i}^{256i+255} x[b,m]*x[b,m+k],  g = b*2048 + i,  k = 0..32.
// 4 lanes per x-block; lane s owns 64 samples + 32 lookahead (static register
// span, no shifting), 2112 unrolled FMAs, 2-level shfl_xor group reduce,
// float4 record stores (lane s owns lags [8s, 8s+8), s==3 also lag 32).
// ---------------------------------------------------------------------------
__global__ __launch_bounds__(256) void blockprod_kernel(const float* __restrict__ in,
                                                        float* __restrict__ B) {
    const int tid = blockIdx.x * 256 + threadIdx.x;
    const int g   = tid >> 2;
    const int s   = tid & 3;
    const int b   = g >> 11;             // NBLK = 2048
    const int i   = g & (NBLK - 1);
    const float* row = in + (size_t)b * T_LEN;
    const int m0 = i * 256 + s * 64;     // reads [m0, m0+96)

    float w[96];
    if (m0 + 96 <= T_LEN) {
        #pragma unroll
        for (int q = 0; q < 24; ++q) {
            const float4 v = *reinterpret_cast<const float4*>(row + m0 + 4 * q);
            w[4*q] = v.x; w[4*q+1] = v.y; w[4*q+2] = v.z; w[4*q+3] = v.w;
        }
    } else {                             // last block, last lane: zero-pad
        #pragma unroll
        for (int q = 0; q < 24; ++q) {
            const int p = m0 + 4 * q;
            float4 v = make_float4(0.f, 0.f, 0.f, 0.f);
            if (p < T_LEN) v = *reinterpret_cast<const float4*>(row + p);
            w[4*q] = v.x; w[4*q+1] = v.y; w[4*q+2] = v.z; w[4*q+3] = v.w;
        }
    }

    float acc[NCODE + 1];
    #pragma unroll
    for (int k = 0; k <= NCODE; ++k) {
        float a = 0.f;
        #pragma unroll
        for (int j = 0; j < 64; ++j) a = fmaf(w[j], w[j + k], a);
        acc[k] = a;
    }

    #pragma unroll
    for (int k = 0; k <= NCODE; ++k) {
        acc[k] += __shfl_xor(acc[k], 1, 64);
        acc[k] += __shfl_xor(acc[k], 2, 64);
    }

    float* rec = B + (size_t)g * RECW;
    if (s == 0) {
        *reinterpret_cast<float4*>(rec + 0) = make_float4(acc[0],  acc[1],  acc[2],  acc[3]);
        *reinterpret_cast<float4*>(rec + 4) = make_float4(acc[4],  acc[5],  acc[6],  acc[7]);
    } else if (s == 1) {
        *reinterpret_cast<float4*>(rec + 8)  = make_float4(acc[8],  acc[9],  acc[10], acc[11]);
        *reinterpret_cast<float4*>(rec + 12) = make_float4(acc[12], acc[13], acc[14], acc[15]);
    } else if (s == 2) {
        *reinterpret_cast<float4*>(rec + 16) = make_float4(acc[16], acc[17], acc[18], acc[19]);
        *reinterpret_cast<float4*>(rec + 20) = make_float4(acc[20], acc[21], acc[22], acc[23]);
    } else {
        *reinterpret_cast<float4*>(rec + 24) = make_float4(acc[24], acc[25], acc[26], acc[27]);
        *reinterpret_cast<float4*>(rec + 28) = make_float4(acc[28], acc[29], acc[30], acc[31]);
        rec[32] = acc[32];
    }
}

// ---------------------------------------------------------------------------
// Pass 2: one thread per frame.
//   corr[k] = sum_{d<4} B[(g0+d)*36 + k]  +  sum_{j<k} u[32-k+j]*(a[j]-c[j])
//   a = x[o..o+32), u = x[o+992..o+1024), c = x[o+1024..o+1056)
// Record loads are 8x float4 + 1 scalar per block -> few, independent VMEM
// ops (vs 132 strided scalars), critical for the 1-wave/SIMD regime.
// Then the r3-validated fully-unrolled Levinson-Durbin, float4 stores.
// ---------------------------------------------------------------------------
__global__ __launch_bounds__(256) void assemble_levinson_kernel(const float* __restrict__ in,
                                                                const float* __restrict__ B,
                                                                float* __restrict__ out) {
    const int t = blockIdx.x * 256 + threadIdx.x;
    if (t >= NFR_TOT) return;
    const int b = t / NFRAMES;
    const int f = t - b * NFRAMES;
    const float* row = in + (size_t)b * T_LEN;
    const int o = f * STRIDE;

    // --- signal pieces for the wrap/tail correction (issue early) ---
    float a[32], u[32], cx[32];
    auto ld4g = [&](int pos, float* dst) {   // pos is a multiple of 4
        float4 v = make_float4(0.f, 0.f, 0.f, 0.f);
        if (pos < T_LEN) v = *reinterpret_cast<const float4*>(row + pos);
        dst[0] = v.x; dst[1] = v.y; dst[2] = v.z; dst[3] = v.w;
    };
    #pragma unroll
    for (int q = 0; q < 8; ++q) ld4g(o + 4 * q,        &a[4 * q]);
    #pragma unroll
    for (int q = 0; q < 8; ++q) ld4g(o + 992 + 4 * q,  &u[4 * q]);
    #pragma unroll
    for (int q = 0; q < 8; ++q) ld4g(o + 1024 + 4 * q, &cx[4 * q]);

    // --- accumulate the 4 block-product records ---
    float F[NCODE + 1];
    #pragma unroll
    for (int k = 0; k <= NCODE; ++k) F[k] = 0.f;

    #pragma unroll
    for (int d = 0; d < 4; ++d) {
        const int i = f + d;
        if (i < NBLK) {                 // blocks past the data are all-zero
            const float* rec = B + (size_t)(b * NBLK + i) * RECW;
            #pragma unroll
            for (int q = 0; q < 8; ++q) {
                const float4 v = *reinterpret_cast<const float4*>(rec + 4 * q);
                F[4*q]   += v.x; F[4*q+1] += v.y;
                F[4*q+2] += v.z; F[4*q+3] += v.w;
            }
            F[32] += rec[32];
        }
    }

    float dd[32];
    #pragma unroll
    for (int j = 0; j < 32; ++j) dd[j] = a[j] - cx[j];

    float corr[NCODE + 1];
    corr[0] = F[0];
    #pragma unroll
    for (int k = 1; k <= NCODE; ++k) {
        float acc2 = F[k];
        #pragma unroll
        for (int j = 0; j < k; ++j) acc2 = fmaf(u[32 - k + j], dd[j], acc2);
        corr[k] = acc2;
    }

    // --- Levinson-Durbin (r3-validated), fully unrolled -> registers only ---
    const float eps = 1e-7f;
    float sol[NCODE + 1];
    const float c0 = fmaxf(corr[0], eps);
    sol[0] = 1.0f;
    sol[1] = -corr[1] / c0;
    float extra = fmaf(corr[1], sol[1], corr[0]);

    #pragma unroll
    for (int k = 1; k < NCODE; ++k) {
        float dot = 0.f;
        #pragma unroll
        for (int i = 0; i <= k; ++i) dot = fmaf(sol[i], corr[k + 1 - i], dot);
        const float lam = -dot / fmaxf(extra, eps);

        float ns[NCODE + 1];
        #pragma unroll
        for (int j = 0; j <= k + 1; ++j) {
            const float av  = (j <= k) ? sol[j] : 0.f;
            const float rev = (j >= 1) ? sol[k + 1 - j] : 0.f;
            ns[j] = fmaf(lam, rev, av);
        }
        #pragma unroll
        for (int j = 0; j <= k + 1; ++j) sol[j] = ns[j];

        extra = (1.f - lam * lam) * extra;
    }

    float* op = out + (size_t)t * NCODE;
    #pragma unroll
    for (int i = 0; i < 8; ++i) {
        *reinterpret_cast<float4*>(op + 4 * i) =
            make_float4(sol[4 * i + 1], sol[4 * i + 2],
                        sol[4 * i + 3], sol[4 * i + 4]);
    }
}

// ---------------------------------------------------------------------------
extern "C" void kernel_launch(void* const* d_in, const int* in_sizes, int n_in,
                              void* d_out, int out_size, void* d_ws, size_t ws_size,
                              hipStream_t stream) {
    const float* in = (const float*)d_in[0];
    float* out      = (float*)d_out;
    float* B        = (float*)d_ws;   // NG * 36 * 4 B = 9.44 MB

    blockprod_kernel<<<NG * 4 / 256, 256, 0, stream>>>(in, B);        // 1024 blocks
    assemble_levinson_kernel<<<(NFR_TOT + 255) / 256, 256, 0, stream>>>(in, B, out);
}

// Round 5
// 42.447 us; speedup vs baseline: 1.1191x; 1.1191x over previous
//
#include <hip/hip_runtime.h>

#define T_LEN   524288
#define BATCH   32
#define WIN     1024
#define STRIDE  256
#define NCODE   32
#define NFRAMES 2049                 // T_LEN/STRIDE + 1
#define NFR_TOT (BATCH * NFRAMES)    // 65568 frames
#define NBLK    2048                 // 256-sample product-blocks per row
#define NG      (BATCH * NBLK)       // 65536 block-product groups

typedef float f32x2 __attribute__((ext_vector_type(2)));

// ---------------------------------------------------------------------------
// Pass 1: lag-block products, lag-plane layout (r3-validated):
//   B[k*NG + g] = sum_{m=256i}^{256i+255} x[b,m]*x[b,m+k],  g = b*2048+i.
// 4 lanes per block; lane s owns samples [64s, 64s+64) + 32 lookahead, kept
// as 48 register float2 pairs. Lag loop packed with v_pk_fma_f32:
//   even j=2q : accE[i] += splat(w2[q].lo) * w2[q+i]      (lags 2i, 2i+1)
//   odd  j=2q+1: accO[i] += splat(w2[q].hi) * w2[q+i+1]   (lags 2i+1, 2i+2)
// op_sel broadcasts fold the splat into the instruction. 1088 FMA-slots/lane
// vs 2112 scalar. 2-level shfl_xor group reduce, coalesced lag-plane stores.
// ---------------------------------------------------------------------------
__global__ __launch_bounds__(256) void blockprod_kernel(const float* __restrict__ in,
                                                        float* __restrict__ B) {
    const int tid = blockIdx.x * 256 + threadIdx.x;
    const int g   = tid >> 2;
    const int s   = tid & 3;
    const int b   = g >> 11;             // NBLK = 2048
    const int i   = g & (NBLK - 1);
    const float* row = in + (size_t)b * T_LEN;
    const int m0 = i * 256 + s * 64;     // reads [m0, m0+96)

    f32x2 w2[48];
    if (m0 + 96 <= T_LEN) {
        #pragma unroll
        for (int q = 0; q < 24; ++q) {
            const float4 v = *reinterpret_cast<const float4*>(row + m0 + 4 * q);
            w2[2*q]   = f32x2{v.x, v.y};
            w2[2*q+1] = f32x2{v.z, v.w};
        }
    } else {                             // last block, last lane: zero-pad
        #pragma unroll
        for (int q = 0; q < 24; ++q) {
            const int p = m0 + 4 * q;
            float4 v = make_float4(0.f, 0.f, 0.f, 0.f);
            if (p < T_LEN) v = *reinterpret_cast<const float4*>(row + p);
            w2[2*q]   = f32x2{v.x, v.y};
            w2[2*q+1] = f32x2{v.z, v.w};
        }
    }

    f32x2 accE[16], accO[16];
    #pragma unroll
    for (int t = 0; t < 16; ++t) { accE[t] = f32x2{0.f, 0.f}; accO[t] = f32x2{0.f, 0.f}; }
    float accE32 = 0.f, accO0 = 0.f;

    #pragma unroll
    for (int q = 0; q < 32; ++q) {
        // even j = 2q: broadcast lo half of w2[q]
        #pragma unroll
        for (int t = 0; t < 16; ++t) {
            asm("v_pk_fma_f32 %0, %1, %2, %0 op_sel:[0,0,0] op_sel_hi:[0,1,1]"
                : "+v"(accE[t]) : "v"(w2[q]), "v"(w2[q + t]));
        }
        accE32 = fmaf(w2[q].x, w2[q + 16].x, accE32);
        // odd j = 2q+1: broadcast hi half of w2[q]
        #pragma unroll
        for (int t = 0; t < 16; ++t) {
            asm("v_pk_fma_f32 %0, %1, %2, %0 op_sel:[1,0,0] op_sel_hi:[1,1,1]"
                : "+v"(accO[t]) : "v"(w2[q]), "v"(w2[q + t + 1]));
        }
        accO0 = fmaf(w2[q].y, w2[q].y, accO0);
    }

    // Recombine pair accumulators into per-lag sums.
    float acc[NCODE + 1];
    acc[0] = accE[0].x + accO0;
    #pragma unroll
    for (int t = 0; t < 16; ++t) acc[2*t + 1] = accE[t].y + accO[t].x;   // odd lags 1..31
    #pragma unroll
    for (int t = 0; t < 15; ++t) acc[2*t + 2] = accE[t + 1].x + accO[t].y; // even lags 2..30
    acc[32] = accE32 + accO[15].y;

    #pragma unroll
    for (int k = 0; k <= NCODE; ++k) {
        acc[k] += __shfl_xor(acc[k], 1, 64);
        acc[k] += __shfl_xor(acc[k], 2, 64);
    }

    // r3-validated coalesced lag-plane stores: lane s owns lags [8s, 8s+8),
    // s==3 also lag 32; same-s lanes store consecutive g.
    if (s == 0) {
        #pragma unroll
        for (int q = 0; q < 8; ++q) B[(size_t)q * NG + g] = acc[q];
    } else if (s == 1) {
        #pragma unroll
        for (int q = 0; q < 8; ++q) B[(size_t)(8 + q) * NG + g] = acc[8 + q];
    } else if (s == 2) {
        #pragma unroll
        for (int q = 0; q < 8; ++q) B[(size_t)(16 + q) * NG + g] = acc[16 + q];
    } else {
        #pragma unroll
        for (int q = 0; q < 9; ++q) B[(size_t)(24 + q) * NG + g] = acc[24 + q];
    }
}

// ---------------------------------------------------------------------------
// Pass 2 (r3-validated, unchanged): one thread per frame.
//   corr[k] = sum_{d<4} B[k][g0+d] + sum_{j<k} u[32-k+j]*(a[j]-c[j])
// then fully-unrolled Levinson-Durbin, float4 stores.
// ---------------------------------------------------------------------------
__global__ __launch_bounds__(256) void assemble_levinson_kernel(const float* __restrict__ in,
                                                                const float* __restrict__ B,
                                                                float* __restrict__ out) {
    const int t = blockIdx.x * 256 + threadIdx.x;
    if (t >= NFR_TOT) return;
    const int b = t / NFRAMES;
    const int f = t - b * NFRAMES;
    const float* row = in + (size_t)b * T_LEN;
    const int o = f * STRIDE;

    float F[NCODE + 1];
    #pragma unroll
    for (int k = 0; k <= NCODE; ++k) F[k] = 0.f;

    #pragma unroll
    for (int d = 0; d < 4; ++d) {
        const int i = f + d;
        if (i < NBLK) {                 // blocks past the data are all-zero
            const float* Bp = B + ((size_t)b * NBLK + i);
            #pragma unroll
            for (int k = 0; k <= NCODE; ++k) F[k] += Bp[(size_t)k * NG];
        }
    }

    float a[32], u[32], cx[32];
    auto ld4g = [&](int pos, float* dst) {   // pos is a multiple of 4
        float4 v = make_float4(0.f, 0.f, 0.f, 0.f);
        if (pos < T_LEN) v = *reinterpret_cast<const float4*>(row + pos);
        dst[0] = v.x; dst[1] = v.y; dst[2] = v.z; dst[3] = v.w;
    };
    #pragma unroll
    for (int q = 0; q < 8; ++q) ld4g(o + 4 * q,        &a[4 * q]);
    #pragma unroll
    for (int q = 0; q < 8; ++q) ld4g(o + 992 + 4 * q,  &u[4 * q]);
    #pragma unroll
    for (int q = 0; q < 8; ++q) ld4g(o + 1024 + 4 * q, &cx[4 * q]);

    float dd[32];
    #pragma unroll
    for (int j = 0; j < 32; ++j) dd[j] = a[j] - cx[j];

    float corr[NCODE + 1];
    corr[0] = F[0];
    #pragma unroll
    for (int k = 1; k <= NCODE; ++k) {
        float acc2 = F[k];
        #pragma unroll
        for (int j = 0; j < k; ++j) acc2 = fmaf(u[32 - k + j], dd[j], acc2);
        corr[k] = acc2;
    }

    const float eps = 1e-7f;
    float sol[NCODE + 1];
    const float c0 = fmaxf(corr[0], eps);
    sol[0] = 1.0f;
    sol[1] = -corr[1] / c0;
    float extra = fmaf(corr[1], sol[1], corr[0]);

    #pragma unroll
    for (int k = 1; k < NCODE; ++k) {
        float dot = 0.f;
        #pragma unroll
        for (int i = 0; i <= k; ++i) dot = fmaf(sol[i], corr[k + 1 - i], dot);
        const float lam = -dot / fmaxf(extra, eps);

        float ns[NCODE + 1];
        #pragma unroll
        for (int j = 0; j <= k + 1; ++j) {
            const float av  = (j <= k) ? sol[j] : 0.f;
            const float rev = (j >= 1) ? sol[k + 1 - j] : 0.f;
            ns[j] = fmaf(lam, rev, av);
        }
        #pragma unroll
        for (int j = 0; j <= k + 1; ++j) sol[j] = ns[j];

        extra = (1.f - lam * lam) * extra;
    }

    float* op = out + (size_t)t * NCODE;
    #pragma unroll
    for (int i = 0; i < 8; ++i) {
        *reinterpret_cast<float4*>(op + 4 * i) =
            make_float4(sol[4 * i + 1], sol[4 * i + 2],
                        sol[4 * i + 3], sol[4 * i + 4]);
    }
}

// ---------------------------------------------------------------------------
extern "C" void kernel_launch(void* const* d_in, const int* in_sizes, int n_in,
                              void* d_out, int out_size, void* d_ws, size_t ws_size,
                              hipStream_t stream) {
    const float* in = (const float*)d_in[0];
    float* out      = (float*)d_out;
    float* B        = (float*)d_ws;   // 33 * 65536 * 4 B = 8.65 MB

    blockprod_kernel<<<NG * 4 / 256, 256, 0, stream>>>(in, B);        // 1024 blocks
    assemble_levinson_kernel<<<(NFR_TOT + 255) / 256, 256, 0, stream>>>(in, B, out);
}